// Round 19
// baseline (92.738 us; speedup 1.0000x reference)
//
#include <hip/hip_runtime.h>

// VQ-VAE vector quantization via bf16-split MFMA, SWAPPED operands.
// Round 19: M=32 per wave -> 4096 waves total = 16 free-running waves/CU
// (r18's no-barrier L2-direct structure at double the TLP). Theory: r17/r18
// both idle the matrix pipe ~70% because 8 waves/CU x 4 dependent chains
// can't tile it; TLP is the missing factor. B-traffic doubles to 1.18GB of
// L2 (34us pipe, overlappable); per-wave VALU halves; VGPR ~90 fits the
// 128 cap of launch_bounds(256,4).
// A = codes -> lane-local argmax (code id in mantissa low 5 bits per chunk).
// nh folded into GEMM via granule 16/17 (zero C-init).
// ws layout (floats):
//   [0..31]          loss partials
//   [2048..34815]    hist partials 32 x 1024
//   [34816..108543]  packed codes: 16 chunks x 4608 floats (18KB):
//                    [18 granules][64 codes][16B]; g0-7 hi, g8-15 lo,
//                    g16 = [nh0,nh1,nh2,0...], g17 = zeros

typedef __attribute__((ext_vector_type(8))) short short8;
typedef __attribute__((ext_vector_type(16))) float f32x16;

#define LOSS_OFF 0
#define PART_OFF 2048
#define PACKED_OFF 34816
#define NPART 32
#define CHUNK_B 18432

__device__ __forceinline__ unsigned short bf16_rne(float v, float& rest) {
  const unsigned u = __float_as_uint(v);
  const unsigned r = u + 0x7fffu + ((u >> 16) & 1u);
  const unsigned short h = (unsigned short)(r >> 16);
  rest = v - __uint_as_float((unsigned)h << 16);
  return h;
}

__global__ void vq_pack(const float* __restrict__ cb0, const float* __restrict__ cb1,
                        float* __restrict__ ws) {
  const int c = blockIdx.x * 256 + threadIdx.x;  // 0..1023
  if (c < NPART) ws[LOSS_OFF + c] = 0.0f;
#pragma unroll
  for (int p = 0; p < NPART; ++p) ws[PART_OFF + p * 1024 + c] = 0.0f;
  const float* row = (c < 512) ? (cb0 + (size_t)c * 64) : (cb1 + (size_t)(c - 512) * 64);
  float v[64];
  float nrm = 0.f;
#pragma unroll
  for (int d = 0; d < 64; d += 4) {
    const float4 f = *(const float4*)(row + d);
    v[d] = f.x; v[d + 1] = f.y; v[d + 2] = f.z; v[d + 3] = f.w;
    nrm += f.x * f.x + f.y * f.y + f.z * f.z + f.w * f.w;
  }
  unsigned short hi[64], lo[64];
#pragma unroll
  for (int d = 0; d < 64; ++d) {
    float rest, dump;
    hi[d] = bf16_rne(v[d], rest);
    lo[d] = bf16_rne(rest, dump);
  }
  float* base = ws + PACKED_OFF + (size_t)(c >> 6) * 4608 + (c & 63) * 4;
#pragma unroll
  for (int g = 0; g < 16; ++g) {
    short8 gr;
#pragma unroll
    for (int e = 0; e < 8; ++e)
      gr[e] = (short)((g < 8) ? hi[g * 8 + e] : lo[(g - 8) * 8 + e]);
    *(short8*)(base + g * 256) = gr;
  }
  {  // g16 = 3-term bf16 split of -0.5||c||^2 ; g17 = zeros (half-1 k-slice)
    const float nh = -0.5f * nrm;
    float r1, r2, dump;
    const unsigned short n0 = bf16_rne(nh, r1);
    const unsigned short n1 = bf16_rne(r1, r2);
    const unsigned short n2 = bf16_rne(r2, dump);
    short8 g16 = {(short)n0, (short)n1, (short)n2, 0, 0, 0, 0, 0};
    *(short8*)(base + 16 * 256) = g16;
    short8 zz = {0, 0, 0, 0, 0, 0, 0, 0};
    *(short8*)(base + 17 * 256) = zz;
  }
}

__global__ __launch_bounds__(256, 4) void vq_dist(
    const float* __restrict__ xin, const int* __restrict__ idxp,
    const float* __restrict__ cb0, const float* __restrict__ cb1,
    float* __restrict__ out, float* __restrict__ ws) {
  __shared__ int qidxL[128];   // ONLY LDS use (epilogue handoff)
  const int tid = threadIdx.x;
  const int w = tid >> 6;      // wave 0..3, owns q w*32..+31
  const int l = tid & 63;
  const int half = l >> 5;
  const int col = l & 31;      // this lane's q within the wave's 32-q tile
  const int blk = blockIdx.x;  // 1024 blocks x 128 q
  const int bb = blk >> 5;
  const int hw0 = (blk & 31) << 7;
  const int nch = (*idxp == 0) ? 8 : 16;

  // ---- x: direct global->reg, B-fragments for this wave's 32-q tile
  short8 xh[4], xl[4];
  float xx;
  {
    float vv[4][8];
    const float* xb =
        xin + ((size_t)(bb * 64 + half * 8)) * 4096 + hw0 + w * 32 + col;
#pragma unroll
    for (int kf = 0; kf < 4; ++kf)
#pragma unroll
      for (int j = 0; j < 8; ++j)
        vv[kf][j] = xb[((size_t)(kf * 16 + j)) * 4096];
    float s = 0.f;
#pragma unroll
    for (int kf = 0; kf < 4; ++kf)
#pragma unroll
      for (int j = 0; j < 8; ++j) {
        const float v = vv[kf][j];
        float rest, dump;
        xh[kf][j] = (short)bf16_rne(v, rest);
        xl[kf][j] = (short)bf16_rne(rest, dump);
        s += v * v;
      }
    s += __shfl_xor(s, 32);  // lanes l, l^32: same q, complementary dims
    xx = s;
  }
  // x~ extension fragment for the nh-granule MFMA: k=0..2 = 1.0 (half-0)
  short8 xnh;
#pragma unroll
  for (int j = 0; j < 8; ++j)
    xnh[j] = (short)((half == 0 && j < 3) ? 0x3F80 : 0);
  const f32x16 ZV = (f32x16)0.0f;  // persistent zero C-input

  // best[r]: packed score, low 5 mantissa bits = 31-(2*chunk+n); fmax
  // prefers smaller code on near-ties; r identity kept by register position.
  float best[16];
#pragma unroll
  for (int r = 0; r < 16; ++r) best[r] = -3.4e38f;

  // per-lane base inside a chunk: code tiles at col*16 (n=0) / +512 (n=1),
  // granule picked by +g*1024; lanes 0-31 read half-0 granule, 32-63 half-1.
  const char* pkl = (const char*)(ws + PACKED_OFF) + col * 16 + half * 1024;

#pragma unroll 2
  for (int i = 0; i < nch; ++i) {
    const char* tb0 = pkl + (size_t)i * CHUNK_B;  // codes 0-31 of chunk
    const char* tb1 = tb0 + 512;                  // codes 32-63

    // nh-granule MFMAs initialize the accumulators (C = ZV)
    const short8 An0 = *(const short8*)(tb0 + 16 * 1024);
    const short8 An1 = *(const short8*)(tb1 + 16 * 1024);
    f32x16 a0 = __builtin_amdgcn_mfma_f32_32x32x16_bf16(An0, xnh, ZV, 0, 0, 0);
    f32x16 a1 = __builtin_amdgcn_mfma_f32_32x32x16_bf16(An1, xnh, ZV, 0, 0, 0);
#pragma unroll
    for (int kf = 0; kf < 4; ++kf) {
      const short8 Ah0 = *(const short8*)(tb0 + (2 * kf) * 1024);
      const short8 Ah1 = *(const short8*)(tb1 + (2 * kf) * 1024);
      const short8 Al0 = *(const short8*)(tb0 + (8 + 2 * kf) * 1024);
      const short8 Al1 = *(const short8*)(tb1 + (8 + 2 * kf) * 1024);
      a0 = __builtin_amdgcn_mfma_f32_32x32x16_bf16(Ah0, xh[kf], a0, 0, 0, 0);
      a1 = __builtin_amdgcn_mfma_f32_32x32x16_bf16(Ah1, xh[kf], a1, 0, 0, 0);
      a0 = __builtin_amdgcn_mfma_f32_32x32x16_bf16(Ah0, xl[kf], a0, 0, 0, 0);
      a1 = __builtin_amdgcn_mfma_f32_32x32x16_bf16(Ah1, xl[kf], a1, 0, 0, 0);
      a0 = __builtin_amdgcn_mfma_f32_32x32x16_bf16(Al0, xh[kf], a0, 0, 0, 0);
      a1 = __builtin_amdgcn_mfma_f32_32x32x16_bf16(Al1, xh[kf], a1, 0, 0, 0);
    }

    // ---- lane-local running argmax (codes on rows -> per-lane regs)
    const unsigned sid0 = (unsigned)(31 - 2 * i);
    const unsigned sid1 = (unsigned)(30 - 2 * i);
#pragma unroll
    for (int r = 0; r < 16; ++r) {
      const float p0 = __uint_as_float((__float_as_uint(a0[r]) & 0xFFFFFFE0u) | sid0);
      const float p1 = __uint_as_float((__float_as_uint(a1[r]) & 0xFFFFFFE0u) | sid1);
      best[r] = fmaxf(fmaxf(p0, p1), best[r]);
    }
  }

  // ---- epilogue: per-lane reduce over 16 regs + one cross-half exchange
  float ls = 0.f;
  {
    float win = best[0];
    int wr = 0;
#pragma unroll
    for (int r = 1; r < 16; ++r) {
      const bool g = best[r] > win;  // tie -> keep lower r (smaller row)
      win = g ? best[r] : win;
      wr = g ? r : wr;
    }
    const unsigned u = __float_as_uint(win);
    const int t = 31 - (int)(u & 31u);
    int code = (t >> 1) * 64 + (t & 1) * 32 + ((wr & 3) + 8 * (wr >> 2) + 4 * half);
    float clean = __uint_as_float(u & 0xFFFFFFE0u);
    const float ocl = __shfl_xor(clean, 32);
    const int oc = __shfl_xor(code, 32);
    const bool take = (ocl > clean) || (ocl == clean && oc < code);
    clean = take ? ocl : clean;
    code = take ? oc : code;
    if (half == 0) {
      qidxL[w * 32 + col] = code;
      ls = xx - 2.0f * clean;  // ||x||^2 - 2(x.c* - 0.5||c*||^2)
    }
  }
#pragma unroll
  for (int mk = 1; mk < 64; mk <<= 1) ls += __shfl_xor(ls, mk);
  if (l == 0) atomicAdd(&ws[LOSS_OFF + (blk & (NPART - 1))], ls);
  __syncthreads();  // qidxL visible to all threads (only block barrier)

  // ---- fused output: histogram partial + gather + NCHW write (coalesced)
  const int q = tid & 127;
  const int dh = tid >> 7;  // 0/1: which 32-d half this thread writes
  const int ci = qidxL[q];
  if (tid < 128) atomicAdd(ws + PART_OFF + (size_t)(blk & (NPART - 1)) * 1024 + ci, 1.0f);
  const float* crow = (ci < 512) ? (cb0 + (size_t)ci * 64) : (cb1 + (size_t)(ci - 512) * 64);
  float cv[32];
#pragma unroll
  for (int d = 0; d < 32; d += 4) {
    const float4 f = *(const float4*)(crow + dh * 32 + d);
    cv[d] = f.x; cv[d + 1] = f.y; cv[d + 2] = f.z; cv[d + 3] = f.w;
  }
  float* ob = out + (((size_t)(bb * 64 + dh * 32)) << 12) + hw0 + q;
#pragma unroll
  for (int d = 0; d < 32; ++d) ob[(size_t)d << 12] = cv[d];
}

__global__ void vq_final(const float* __restrict__ ws, float* __restrict__ out) {
  __shared__ float sred[256];
  const int t = threadIdx.x;
  float h = 0.f;
#pragma unroll
  for (int i = t; i < 1024; i += 256) {
    float s = 0.f;
#pragma unroll
    for (int p = 0; p < NPART; ++p) s += ws[PART_OFF + p * 1024 + i];
    const float avg = s * (1.0f / 131072.0f);
    h += avg * logf(avg + 1e-10f);
  }
  sred[t] = h;
  __syncthreads();
  for (int s2 = 128; s2 > 0; s2 >>= 1) {
    if (t < s2) sred[t] += sred[t + s2];
    __syncthreads();
  }
  if (t == 0) {
    float lsum = 0.f;
#pragma unroll
    for (int p = 0; p < NPART; ++p) lsum += ws[LOSS_OFF + p];
    out[8388608] = 1.25f * lsum * (1.0f / 8388608.0f);
    out[8388609] = expf(-sred[0]);
  }
}

extern "C" void kernel_launch(void* const* d_in, const int* in_sizes, int n_in,
                              void* d_out, int out_size, void* d_ws, size_t ws_size,
                              hipStream_t stream) {
  (void)in_sizes; (void)n_in; (void)out_size; (void)ws_size;
  const float* xin = (const float*)d_in[0];
  const float* cb0 = (const float*)d_in[1];
  const float* cb1 = (const float*)d_in[2];
  const int* idxp = (const int*)d_in[3];
  float* out = (float*)d_out;
  float* ws = (float*)d_ws;

  vq_pack<<<4, 256, 0, stream>>>(cb0, cb1, ws);
  vq_dist<<<1024, 256, 0, stream>>>(xin, idxp, cb0, cb1, out, ws);
  vq_final<<<1, 256, 0, stream>>>(ws, out);
}

// Round 20
// 75.268 us; speedup vs baseline: 1.2321x; 1.2321x over previous
//
#include <hip/hip_runtime.h>

// VQ-VAE vector quantization, bf16-split MFMA, 16x16x32 shape (round 20).
// Diagnosis: r13's pure-MFMA ablation ran 2x the issue bound -> dependent-
// chain latency with only 2 accumulator chains was the cap. 16x16x32 gives
// 16 accs/wave (4 t-phases x 4 concurrent chains, depth 6) at ~12% more
// issue. nh = -0.5||c||^2 enters as EXACT fp32 C-init (pre-packed in C
// fragment layout). Shell = r17: ring-3 LDS staging via global_load_lds,
// counted vmcnt(5), 1 barrier/chunk, fused gather+hist+NCHW epilogue.
// ws layout (floats):
//   [0..31]          loss partials
//   [2048..34815]    hist partials 32 x 1024
//   [34816..116735]  packed codes: 16 chunks x 5120 floats (20KB):
//     per chunk: 4 t-blocks (16 codes) x 1280 floats:
//       [f0hi 256][f1hi 256][f0lo 256][f1lo 256][nhC 256]
//     A-frag elem (code cl=c&15, k=f*32+g*8+j) at g*64+cl*4 (+j bf16)
//     nhC: lane l gets float4 nh[t*16+(l>>4)*4+r] at l*4+r

typedef __attribute__((ext_vector_type(8))) short short8;
typedef __attribute__((ext_vector_type(4))) float f32x4;

#define LOSS_OFF 0
#define PART_OFF 2048
#define PACKED_OFF 34816
#define NPART 32
#define CHUNK_B 20480

#define GLL16(gsrc, ldst)                                                      \
  __builtin_amdgcn_global_load_lds(                                            \
      (const __attribute__((address_space(1))) void*)(gsrc),                   \
      (__attribute__((address_space(3))) void*)(ldst), 16, 0, 0)

__device__ __forceinline__ unsigned short bf16_rne(float v, float& rest) {
  const unsigned u = __float_as_uint(v);
  const unsigned r = u + 0x7fffu + ((u >> 16) & 1u);
  const unsigned short h = (unsigned short)(r >> 16);
  rest = v - __uint_as_float((unsigned)h << 16);
  return h;
}

__global__ void vq_pack(const float* __restrict__ cb0, const float* __restrict__ cb1,
                        float* __restrict__ ws) {
  const int c = blockIdx.x * 256 + threadIdx.x;  // 0..1023
  if (c < NPART) ws[LOSS_OFF + c] = 0.0f;
#pragma unroll
  for (int p = 0; p < NPART; ++p) ws[PART_OFF + p * 1024 + c] = 0.0f;
  const float* row = (c < 512) ? (cb0 + (size_t)c * 64) : (cb1 + (size_t)(c - 512) * 64);
  float v[64];
  float nrm = 0.f;
#pragma unroll
  for (int d = 0; d < 64; d += 4) {
    const float4 f = *(const float4*)(row + d);
    v[d] = f.x; v[d + 1] = f.y; v[d + 2] = f.z; v[d + 3] = f.w;
    nrm += f.x * f.x + f.y * f.y + f.z * f.z + f.w * f.w;
  }
  unsigned short hi[64], lo[64];
#pragma unroll
  for (int d = 0; d < 64; ++d) {
    float rest, dump;
    hi[d] = bf16_rne(v[d], rest);
    lo[d] = bf16_rne(rest, dump);
  }
  const int ch = c >> 6, t = (c >> 4) & 3, cl16 = c & 15;
  float* tb = ws + PACKED_OFF + (size_t)ch * 5120 + t * 1280;
#pragma unroll
  for (int fi = 0; fi < 4; ++fi) {  // 0=f0hi 1=f1hi 2=f0lo 3=f1lo
    const int f = fi & 1;
    const int isLo = fi >> 1;
#pragma unroll
    for (int g = 0; g < 4; ++g) {
      short8 gr;
#pragma unroll
      for (int j = 0; j < 8; ++j) {
        const int k = f * 32 + g * 8 + j;
        gr[j] = (short)(isLo ? lo[k] : hi[k]);
      }
      *(short8*)(tb + fi * 256 + g * 64 + cl16 * 4) = gr;
    }
  }
  {  // nhC: C-layout broadcast (row = (l>>4)*4 + r)
    const float nh = -0.5f * nrm;
    const int lg = cl16 >> 2;  // lane-group holding this code's row
    const int r = cl16 & 3;
    float* nb = tb + 1024 + r;
#pragma unroll
    for (int cc = 0; cc < 16; ++cc) nb[(lg * 16 + cc) * 4] = nh;
  }
}

__global__ __launch_bounds__(256, 2) void vq_dist(
    const float* __restrict__ xin, const int* __restrict__ idxp,
    const float* __restrict__ cb0, const float* __restrict__ cb1,
    float* __restrict__ out, float* __restrict__ ws) {
  __shared__ char smem[62464];  // 3 x 20KB ring + 1KB qidx
  char* ring = smem;
  int* qidxL = (int*)(smem + 61440);
  const int tid = threadIdx.x;
  const int w = tid >> 6;      // wave 0..3, owns q w*64..+63
  const int l = tid & 63;
  const int lg = l >> 4;       // k-octet / row-group selector
  const int c16 = l & 15;      // q (B cols) / code row (A) within tile
  const int blk = blockIdx.x;  // 512 blocks x 256 q
  const int bb = blk >> 4;
  const int hw0 = (blk & 15) << 8;
  const int nch = (*idxp == 0) ? 8 : 16;
  const char* pk = (const char*)(ws + PACKED_OFF);

  // stage chunk: 20KB over 4 waves -> 5 x 1KB GLL per wave
  auto stage = [&](int ch, int buf) {
    const char* src = pk + (size_t)ch * CHUNK_B + w * 5120 + l * 16;
    char* dst = ring + buf * CHUNK_B + w * 5120;
#pragma unroll
    for (int i = 0; i < 5; ++i) GLL16(src + i * 1024, dst + i * 1024);
  };
  stage(0, 0);
  stage(1, 1);  // 10 outstanding/wave; latency hides under x prologue

  // ---- x -> B fragments (col=c16, k = f*32 + lg*8 + j), 4 m-tiles
  short8 xh[4][2], xl[4][2];
  float xs[4];
#pragma unroll
  for (int m = 0; m < 4; ++m) {
    const float* base =
        xin + ((size_t)(bb * 64 + lg * 8)) * 4096 + hw0 + w * 64 + m * 16 + c16;
    float vv[2][8];
#pragma unroll
    for (int f = 0; f < 2; ++f)
#pragma unroll
      for (int j = 0; j < 8; ++j)
        vv[f][j] = base[((size_t)(f * 32 + j)) * 4096];
    float s = 0.f;
#pragma unroll
    for (int f = 0; f < 2; ++f)
#pragma unroll
      for (int j = 0; j < 8; ++j) {
        const float v = vv[f][j];
        float rest, dump;
        xh[m][f][j] = (short)bf16_rne(v, rest);
        xl[m][f][j] = (short)bf16_rne(rest, dump);
        s += v * v;
      }
    xs[m] = s;  // partial: k = lg*8..+8 per f; reduced over lane-groups later
  }

  // best[m]: packed score, low 8 mantissa bits = 255-(chunk*16+t*4+r).
  // fmax prefers higher score, then smaller (chunk,t,r) => smaller code.
  float best[4];
#pragma unroll
  for (int m = 0; m < 4; ++m) best[m] = -3.4e38f;

  const int la = lg * 256 + c16 * 16;  // A-frag lane byte offset

  for (int i = 0; i < nch; ++i) {
    if (i < nch - 1) {
      asm volatile("s_waitcnt vmcnt(5)" ::: "memory");  // chunk i landed
    } else {
      asm volatile("s_waitcnt vmcnt(0)" ::: "memory");
    }
    __builtin_amdgcn_s_barrier();  // chunk i resident; chunk i-1 consumed
    if (i + 2 < nch) stage(i + 2, (i + 2) % 3);  // refills buf[(i-1)%3]: safe

    const char* bufp = ring + (i % 3) * CHUNK_B;
#pragma unroll
    for (int t = 0; t < 4; ++t) {
      const char* tb = bufp + t * 5120;
      const short8 ch0 = *(const short8*)(tb + la);
      const short8 ch1 = *(const short8*)(tb + 1024 + la);
      const short8 cl0 = *(const short8*)(tb + 2048 + la);
      const short8 cl1 = *(const short8*)(tb + 3072 + la);
      const f32x4 nC = *(const f32x4*)(tb + 4096 + l * 16);
      f32x4 a0 = nC, a1 = nC, a2 = nC, a3 = nC;  // 4 independent chains
      a0 = __builtin_amdgcn_mfma_f32_16x16x32_bf16(ch0, xh[0][0], a0, 0, 0, 0);
      a1 = __builtin_amdgcn_mfma_f32_16x16x32_bf16(ch0, xh[1][0], a1, 0, 0, 0);
      a2 = __builtin_amdgcn_mfma_f32_16x16x32_bf16(ch0, xh[2][0], a2, 0, 0, 0);
      a3 = __builtin_amdgcn_mfma_f32_16x16x32_bf16(ch0, xh[3][0], a3, 0, 0, 0);
      a0 = __builtin_amdgcn_mfma_f32_16x16x32_bf16(ch1, xh[0][1], a0, 0, 0, 0);
      a1 = __builtin_amdgcn_mfma_f32_16x16x32_bf16(ch1, xh[1][1], a1, 0, 0, 0);
      a2 = __builtin_amdgcn_mfma_f32_16x16x32_bf16(ch1, xh[2][1], a2, 0, 0, 0);
      a3 = __builtin_amdgcn_mfma_f32_16x16x32_bf16(ch1, xh[3][1], a3, 0, 0, 0);
      a0 = __builtin_amdgcn_mfma_f32_16x16x32_bf16(ch0, xl[0][0], a0, 0, 0, 0);
      a1 = __builtin_amdgcn_mfma_f32_16x16x32_bf16(ch0, xl[1][0], a1, 0, 0, 0);
      a2 = __builtin_amdgcn_mfma_f32_16x16x32_bf16(ch0, xl[2][0], a2, 0, 0, 0);
      a3 = __builtin_amdgcn_mfma_f32_16x16x32_bf16(ch0, xl[3][0], a3, 0, 0, 0);
      a0 = __builtin_amdgcn_mfma_f32_16x16x32_bf16(ch1, xl[0][1], a0, 0, 0, 0);
      a1 = __builtin_amdgcn_mfma_f32_16x16x32_bf16(ch1, xl[1][1], a1, 0, 0, 0);
      a2 = __builtin_amdgcn_mfma_f32_16x16x32_bf16(ch1, xl[2][1], a2, 0, 0, 0);
      a3 = __builtin_amdgcn_mfma_f32_16x16x32_bf16(ch1, xl[3][1], a3, 0, 0, 0);
      a0 = __builtin_amdgcn_mfma_f32_16x16x32_bf16(cl0, xh[0][0], a0, 0, 0, 0);
      a1 = __builtin_amdgcn_mfma_f32_16x16x32_bf16(cl0, xh[1][0], a1, 0, 0, 0);
      a2 = __builtin_amdgcn_mfma_f32_16x16x32_bf16(cl0, xh[2][0], a2, 0, 0, 0);
      a3 = __builtin_amdgcn_mfma_f32_16x16x32_bf16(cl0, xh[3][0], a3, 0, 0, 0);
      a0 = __builtin_amdgcn_mfma_f32_16x16x32_bf16(cl1, xh[0][1], a0, 0, 0, 0);
      a1 = __builtin_amdgcn_mfma_f32_16x16x32_bf16(cl1, xh[1][1], a1, 0, 0, 0);
      a2 = __builtin_amdgcn_mfma_f32_16x16x32_bf16(cl1, xh[2][1], a2, 0, 0, 0);
      a3 = __builtin_amdgcn_mfma_f32_16x16x32_bf16(cl1, xh[3][1], a3, 0, 0, 0);

      const unsigned bs = 255u - (unsigned)(i * 16 + t * 4);
#pragma unroll
      for (int r = 0; r < 4; ++r) {
        const float p0 = __uint_as_float((__float_as_uint(a0[r]) & 0xFFFFFF00u) | (bs - r));
        const float p1 = __uint_as_float((__float_as_uint(a1[r]) & 0xFFFFFF00u) | (bs - r));
        const float p2 = __uint_as_float((__float_as_uint(a2[r]) & 0xFFFFFF00u) | (bs - r));
        const float p3 = __uint_as_float((__float_as_uint(a3[r]) & 0xFFFFFF00u) | (bs - r));
        best[0] = fmaxf(best[0], p0);
        best[1] = fmaxf(best[1], p1);
        best[2] = fmaxf(best[2], p2);
        best[3] = fmaxf(best[3], p3);
      }
    }
  }

  // ---- epilogue: decode ids, reduce over the 4 lane-groups (xor 16, 32)
  float ls = 0.f;
#pragma unroll
  for (int m = 0; m < 4; ++m) {
    const unsigned u = __float_as_uint(best[m]);
    const int iid = 255 - (int)(u & 255u);
    int code = (iid >> 4) * 64 + ((iid >> 2) & 3) * 16 + lg * 4 + (iid & 3);
    float clean = __uint_as_float(u & 0xFFFFFF00u);
    float xsm = xs[m];
#pragma unroll
    for (int mk = 16; mk < 64; mk <<= 1) {
      const float ocl = __shfl_xor(clean, mk);
      const int oc = __shfl_xor(code, mk);
      const float oxs = __shfl_xor(xsm, mk);
      xsm += oxs;
      const bool take = (ocl > clean) || (ocl == clean && oc < code);
      clean = take ? ocl : clean;
      code = take ? oc : code;
    }
    if (l < 16) {
      qidxL[w * 64 + m * 16 + l] = code;
      ls += xsm - 2.0f * clean;  // ||x||^2 - 2(x.c* - 0.5||c*||^2)
    }
  }
#pragma unroll
  for (int mk = 1; mk < 64; mk <<= 1) ls += __shfl_xor(ls, mk);
  if (l == 0) atomicAdd(&ws[LOSS_OFF + (blk & (NPART - 1))], ls);
  __syncthreads();  // qidxL visible to all threads

  // ---- fused output: histogram partial + gather + NCHW write (coalesced)
  const int ci = qidxL[tid];
  atomicAdd(ws + PART_OFF + (size_t)(blk & (NPART - 1)) * 1024 + ci, 1.0f);
  const float* crow = (ci < 512) ? (cb0 + (size_t)ci * 64) : (cb1 + (size_t)(ci - 512) * 64);
  float* ob = out + (((size_t)(bb * 64)) << 12) + hw0 + tid;
#pragma unroll
  for (int d4 = 0; d4 < 16; ++d4) {
    const float4 f = *(const float4*)(crow + d4 * 4);
    ob[((size_t)(d4 * 4 + 0)) << 12] = f.x;
    ob[((size_t)(d4 * 4 + 1)) << 12] = f.y;
    ob[((size_t)(d4 * 4 + 2)) << 12] = f.z;
    ob[((size_t)(d4 * 4 + 3)) << 12] = f.w;
  }
}

__global__ void vq_final(const float* __restrict__ ws, float* __restrict__ out) {
  __shared__ float sred[256];
  const int t = threadIdx.x;
  float h = 0.f;
#pragma unroll
  for (int i = t; i < 1024; i += 256) {
    float s = 0.f;
#pragma unroll
    for (int p = 0; p < NPART; ++p) s += ws[PART_OFF + p * 1024 + i];
    const float avg = s * (1.0f / 131072.0f);
    h += avg * logf(avg + 1e-10f);
  }
  sred[t] = h;
  __syncthreads();
  for (int s2 = 128; s2 > 0; s2 >>= 1) {
    if (t < s2) sred[t] += sred[t + s2];
    __syncthreads();
  }
  if (t == 0) {
    float lsum = 0.f;
#pragma unroll
    for (int p = 0; p < NPART; ++p) lsum += ws[LOSS_OFF + p];
    out[8388608] = 1.25f * lsum * (1.0f / 8388608.0f);
    out[8388609] = expf(-sred[0]);
  }
}

extern "C" void kernel_launch(void* const* d_in, const int* in_sizes, int n_in,
                              void* d_out, int out_size, void* d_ws, size_t ws_size,
                              hipStream_t stream) {
  (void)in_sizes; (void)n_in; (void)out_size; (void)ws_size;
  const float* xin = (const float*)d_in[0];
  const float* cb0 = (const float*)d_in[1];
  const float* cb1 = (const float*)d_in[2];
  const int* idxp = (const int*)d_in[3];
  float* out = (float*)d_out;
  float* ws = (float*)d_ws;

  vq_pack<<<4, 256, 0, stream>>>(cb0, cb1, ws);
  vq_dist<<<512, 256, 0, stream>>>(xin, idxp, cb0, cb1, out, ws);
  vq_final<<<1, 256, 0, stream>>>(ws, out);
}